// Round 2
// baseline (2136.796 us; speedup 1.0000x reference)
//
#include <hip/hip_runtime.h>

#define B_    4
#define N_    8192
#define CIN   128
#define COUT  256
#define M_    2048
#define K_    16
#define DM    64
#define MAXNN 64
#define CAP   128
#define R2    0.01f
#define EXT   0.1f

typedef float v2f __attribute__((ext_vector_type(2)));
typedef unsigned long long ull;

// Exact-rounded squared distance matching numpy's op order: (dx*dx + dy*dy) + dz*dz
__device__ __forceinline__ float d2_exact(float ax, float ay, float az,
                                          float bx, float by, float bz) {
    float dx = ax - bx, dy = ay - by, dz = az - bz;
    return __fadd_rn(__fadd_rn(__fmul_rn(dx, dx), __fmul_rn(dy, dy)), __fmul_rn(dz, dz));
}

__device__ __forceinline__ ull kmax(ull a, ull b) { return a > b ? a : b; }

// Raw workgroup barrier: drain LDS only (lgkmcnt), NOT vmcnt.
// __syncthreads would wait vmcnt(0) too, putting wave0's fire-and-forget global
// stores (idx_out/out_pos) on the serial chain every iteration. Nobody reads
// those until kernel end, so skipping the vmem drain is safe; "memory" clobber
// keeps all LDS ops ordered around the barrier.
#define BAR_LDS() asm volatile("s_waitcnt lgkmcnt(0)\n\ts_barrier" ::: "memory")

// DPP u64-key max step (key only: 2 regs through the butterfly)
#define DPP_STEP2(CTRL)                                                                   \
    {                                                                                     \
        unsigned tlo = (unsigned)__builtin_amdgcn_update_dpp(0, (int)klo, CTRL, 0xF, 0xF, true); \
        unsigned thi = (unsigned)__builtin_amdgcn_update_dpp(0, (int)khi, CTRL, 0xF, 0xF, true); \
        unsigned long long tk = ((unsigned long long)thi << 32) | tlo;                    \
        unsigned long long ck = ((unsigned long long)khi << 32) | klo;                    \
        if (tk > ck) { klo = tlo; khi = thi; }                                            \
    }

// ---------------- K1 (merged): blocks 0..3 = FPS (one per cloud); blocks >=4 = pre-MLP ----
// FPS: 512 threads (8 waves), 16 pts/lane as 8 x float2 => 64 data VGPRs.
// Serial chain per iteration (2047 iters):
//   packed mind-update -> u64-key depth-4 tree (lane argmax) -> 6-step DPP ->
//   per-wave slot write -> raw lgkm-only barrier -> 8-key tree -> LDS coord bcast.
// u64 key = value||~idx; u64 max == numpy argmax with first-index ties (keys unique).
// Update arithmetic identical (packed f32, contract off) => bit-exact FPS selection.
__global__ __launch_bounds__(512, 2) void fps_pre_kernel(const float* __restrict__ pos,
                                                         int* __restrict__ idx_out,
                                                         float* __restrict__ out_pos,
                                                         const float* __restrict__ x,
                                                         const float* __restrict__ Wp,
                                                         const float* __restrict__ bvec,
                                                         float* __restrict__ xpre) {
    __shared__ union {
        struct { float sp[N_ * 3]; ull slots[2][8]; } f;   // 96 KB + 128 B
        struct { float Ws[CIN * DM]; float xs[32][CIN]; } p;  // 48 KB
    } sh;

    const int t = threadIdx.x;

    if (blockIdx.x >= 4) {
        // ---------------- pre-MLP branch: 32 rows per block ----------------
        const size_t rowBase = (size_t)(blockIdx.x - 4) * 32;
        for (int i = t; i < CIN * DM; i += 512) sh.p.Ws[i] = Wp[i];
        for (int i = t; i < 32 * CIN; i += 512) {
            int r = i >> 7, c = i & 127;
            sh.p.xs[r][c] = x[(rowBase + r) * CIN + c];
        }
        __syncthreads();
        const int col = t & 63, r0 = t >> 6;   // r0 in [0,8)
        float acc[4];
        float bias = bvec[col];
#pragma unroll
        for (int rr = 0; rr < 4; rr++) acc[rr] = bias;
        for (int c = 0; c < CIN; c++) {
            float w = sh.p.Ws[c * DM + col];
#pragma unroll
            for (int rr = 0; rr < 4; rr++) acc[rr] = fmaf(sh.p.xs[r0 + 8 * rr][c], w, acc[rr]);
        }
#pragma unroll
        for (int rr = 0; rr < 4; rr++) xpre[(rowBase + r0 + 8 * rr) * DM + col] = acc[rr];
        return;
    }

    // ---------------- FPS branch ----------------
    const int b = blockIdx.x;
    const float* pb = pos + (size_t)b * N_ * 3;

    v2f px[8], py[8], pz[8], mind[8];
#pragma unroll
    for (int jj = 0; jj < 8; jj++) {
        int n0 = t + (2 * jj) * 512, n1 = n0 + 512;
        float x0 = pb[n0 * 3 + 0], y0 = pb[n0 * 3 + 1], z0 = pb[n0 * 3 + 2];
        float x1 = pb[n1 * 3 + 0], y1 = pb[n1 * 3 + 1], z1 = pb[n1 * 3 + 2];
        px[jj] = (v2f){x0, x1};
        py[jj] = (v2f){y0, y1};
        pz[jj] = (v2f){z0, z1};
        mind[jj] = (v2f){1e30f, 1e30f};
        // stage position cloud into LDS, packed [3n] (bit-identical copy)
        sh.f.sp[n0 * 3 + 0] = x0; sh.f.sp[n0 * 3 + 1] = y0; sh.f.sp[n0 * 3 + 2] = z0;
        sh.f.sp[n1 * 3 + 0] = x1; sh.f.sp[n1 * 3 + 1] = y1; sh.f.sp[n1 * 3 + 2] = z1;
    }
    // loop-invariant low words of the per-slot u64 keys: ~global_index
    unsigned kloc[16];
#pragma unroll
    for (int s = 0; s < 16; s++) kloc[s] = ~(unsigned)(t + (s << 9));

    float cx = pb[0], cy = pb[1], cz = pb[2];
    if (t == 0) {
        idx_out[b * M_ + 0] = 0;
        float* op = out_pos + ((size_t)(b * M_ + 0)) * 3;
        op[0] = cx; op[1] = cy; op[2] = cz;
    }
    BAR_LDS();

    for (int m = 1; m < M_; m++) {
        // fused mind-update (exact packed f32, contract off) producing 16 values
        float nv[16];
        {
#pragma clang fp contract(off)
            v2f cx2 = (v2f){cx, cx}, cy2 = (v2f){cy, cy}, cz2 = (v2f){cz, cz};
#pragma unroll
            for (int jj = 0; jj < 8; jj++) {
                v2f dx = px[jj] - cx2, dy = py[jj] - cy2, dz = pz[jj] - cz2;
                v2f d = (dx * dx + dy * dy) + dz * dz;
                v2f mo = mind[jj];
                float n0 = fminf(mo.x, d.x);
                float n1 = fminf(mo.y, d.y);
                mind[jj] = (v2f){n0, n1};
                nv[2 * jj] = n0; nv[2 * jj + 1] = n1;
            }
        }
        // lane-local argmax as depth-4 u64-key max tree (chain ~32cy vs 16-deep
        // cmp+select chain). Keys unique => exact numpy first-index semantics.
        ull L[16];
#pragma unroll
        for (int s = 0; s < 16; s++)
            L[s] = ((ull)__float_as_uint(nv[s]) << 32) | kloc[s];
        ull q0 = kmax(L[0], L[1]),  q1 = kmax(L[2], L[3]);
        ull q2 = kmax(L[4], L[5]),  q3 = kmax(L[6], L[7]);
        ull q4 = kmax(L[8], L[9]),  q5 = kmax(L[10], L[11]);
        ull q6 = kmax(L[12], L[13]), q7 = kmax(L[14], L[15]);
        ull r0 = kmax(q0, q1), r1 = kmax(q2, q3), r2 = kmax(q4, q5), r3 = kmax(q6, q7);
        ull s0 = kmax(r0, r1), s1 = kmax(r2, r3);
        ull lk = kmax(s0, s1);
        unsigned klo = (unsigned)lk;
        unsigned khi = (unsigned)(lk >> 32);

        // wave64 max-reduce via DPP; winner lands in lane 63
        DPP_STEP2(0x111)  // row_shr:1
        DPP_STEP2(0x112)  // row_shr:2
        DPP_STEP2(0x114)  // row_shr:4
        DPP_STEP2(0x118)  // row_shr:8
        DPP_STEP2(0x142)  // row_bcast:15
        DPP_STEP2(0x143)  // row_bcast:31

        // per-wave slot write (double-buffered on m&1; raw barrier drains lgkm
        // per-wave before release, so buffer reuse 2 iters later is safe)
        ull* sl = sh.f.slots[m & 1];
        if ((t & 63) == 63) sl[t >> 6] = ((ull)khi << 32) | klo;
        BAR_LDS();

        // all threads: depth-3 max tree over the 8 wave keys
        ull w0 = kmax(sl[0], sl[1]), w1 = kmax(sl[2], sl[3]);
        ull w2 = kmax(sl[4], sl[5]), w3 = kmax(sl[6], sl[7]);
        ull kk = kmax(kmax(w0, w1), kmax(w2, w3));

        const unsigned widx = ~(unsigned)(kk & 0xFFFFFFFFull);
        // winner coords: same-address LDS broadcast (packed triple)
        const float* c3 = &sh.f.sp[widx * 3];
        cx = c3[0]; cy = c3[1]; cz = c3[2];
        if (t == 0) {
            idx_out[b * M_ + m] = (int)widx;
            float* op = out_pos + ((size_t)(b * M_ + m)) * 3;
            op[0] = cx; op[1] = cy; op[2] = cz;
        }
    }
}

// ---------------- K3: fused neighbor search + KPConv + post + shortcut ----------------
__global__ __launch_bounds__(256) void conv_kernel(const float* __restrict__ pos,
                                                   const float* __restrict__ x,
                                                   const float* __restrict__ xpre,
                                                   const int* __restrict__ idxs,
                                                   const float* __restrict__ kp_pos,
                                                   const float* __restrict__ kp_W,
                                                   const float* __restrict__ W_post,
                                                   const float* __restrict__ b_post,
                                                   const float* __restrict__ W_sc,
                                                   const float* __restrict__ b_sc,
                                                   float* __restrict__ out_feat) {
    const int blk = blockIdx.x;
    const int b = blk / M_;
    const int m = blk % M_;
    const int t = threadIdx.x;

    __shared__ int   nIdx[CAP];
    __shared__ float nD2[CAP];
    __shared__ int   cntS;
    __shared__ float infl[MAXNN][K_];   // 4 KB
    __shared__ float xj[MAXNN][DM];     // 16 KB
    __shared__ float sS[K_ * DM];       // 4 KB
    __shared__ float featP[4][DM];      // 1 KB
    __shared__ float xg[CIN];           // 0.5 KB

    const float* pb = pos + (size_t)b * N_ * 3;
    const int ctr = idxs[b * M_ + m];
    const float cx = pb[ctr * 3 + 0], cy = pb[ctr * 3 + 1], cz = pb[ctr * 3 + 2];

    if (t == 0) cntS = 0;
    __syncthreads();

    // neighbor scan over all N points
    for (int j = 0; j < N_ / 256; j++) {
        int n = j * 256 + t;
        float x0 = pb[n * 3 + 0], y0 = pb[n * 3 + 1], z0 = pb[n * 3 + 2];
        float d = d2_exact(x0, y0, z0, cx, cy, cz);
        if (d <= R2) {
            int p = atomicAdd(&cntS, 1);
            if (p < CAP) { nIdx[p] = n; nD2[p] = d; }
        }
    }
    __syncthreads();
    int cnt = cntS; if (cnt > CAP) cnt = CAP;
    if (cnt > MAXNN) {
        // rare path: keep the 64 lexicographically-smallest (d2, idx) = stable top_k
        if (t == 0) {
            for (int s = 0; s < MAXNN; s++) {
                int best = s;
                for (int q = s + 1; q < cnt; q++) {
                    if (nD2[q] < nD2[best] || (nD2[q] == nD2[best] && nIdx[q] < nIdx[best])) best = q;
                }
                float td = nD2[best]; nD2[best] = nD2[s]; nD2[s] = td;
                int ti = nIdx[best]; nIdx[best] = nIdx[s]; nIdx[s] = ti;
            }
        }
        __syncthreads();
        cnt = MAXNN;
    }

    // influence weights (one thread per neighbor)
    if (t < cnt) {
        int n = nIdx[t];
        float rx = pb[n * 3 + 0] - cx, ry = pb[n * 3 + 1] - cy, rz = pb[n * 3 + 2] - cz;
#pragma unroll
        for (int k = 0; k < K_; k++) {
            float dx = rx - kp_pos[k * 3 + 0];
            float dy = ry - kp_pos[k * 3 + 1];
            float dz = rz - kp_pos[k * 3 + 2];
            float dist = sqrtf(dx * dx + dy * dy + dz * dz + 1e-12f);
            infl[t][k] = fmaxf(1.0f - dist / EXT, 0.0f);
        }
    }
    // stage gathered neighbor features
    for (int i = t; i < cnt * DM; i += 256) {
        int e = i >> 6, d = i & 63;
        xj[e][d] = xpre[((size_t)b * N_ + nIdx[e]) * DM + d];
    }
    __syncthreads();

    // s[k][d] = sum_e infl[e][k] * xj[e][d]
#pragma unroll
    for (int p = 0; p < 4; p++) {
        int pair = t + p * 256;
        int k = pair >> 6, d = pair & 63;
        float acc = 0.f;
        for (int e = 0; e < cnt; e++) acc = fmaf(infl[e][k], xj[e][d], acc);
        sS[pair] = acc;
    }
    __syncthreads();

    // feat[d'] = sum_{k,d} s[k][d] * kp_W[k][d][d']  (4-way k-split)
    {
        int dprime = t & 63, ks = t >> 6;
        float acc = 0.f;
        for (int k = ks * 4; k < ks * 4 + 4; k++) {
            const float* kw = kp_W + ((size_t)k * DM) * DM + dprime;
#pragma unroll
            for (int d = 0; d < DM; d++) acc = fmaf(sS[k * DM + d], kw[d * DM], acc);
        }
        featP[ks][dprime] = acc;
    }
    __syncthreads();
    if (t < DM) featP[0][t] = featP[0][t] + featP[1][t] + featP[2][t] + featP[3][t];
    if (t < CIN) xg[t] = x[((size_t)b * N_ + ctr) * CIN + t];
    __syncthreads();

    // out[o] = feat @ W_post + b_post + x[ctr] @ W_sc + b_sc
    {
        const int o = t;
        float acc = b_post[o] + b_sc[o];
#pragma unroll 8
        for (int d = 0; d < DM; d++) acc = fmaf(featP[0][d], W_post[d * COUT + o], acc);
#pragma unroll 8
        for (int c = 0; c < CIN; c++) acc = fmaf(xg[c], W_sc[c * COUT + o], acc);
        out_feat[((size_t)(b * M_ + m)) * COUT + o] = acc;
    }
}

extern "C" void kernel_launch(void* const* d_in, const int* in_sizes, int n_in,
                              void* d_out, int out_size, void* d_ws, size_t ws_size,
                              hipStream_t stream) {
    const float* x      = (const float*)d_in[0];
    const float* pos    = (const float*)d_in[1];
    const float* W_pre  = (const float*)d_in[2];
    const float* b_pre  = (const float*)d_in[3];
    const float* kp_pos = (const float*)d_in[4];
    const float* kp_W   = (const float*)d_in[5];
    const float* W_post = (const float*)d_in[6];
    const float* b_post = (const float*)d_in[7];
    const float* W_sc   = (const float*)d_in[8];
    const float* b_sc   = (const float*)d_in[9];

    float* out_feat = (float*)d_out;
    float* out_pos  = (float*)d_out + (size_t)B_ * M_ * COUT;

    int*   idxs = (int*)d_ws;
    float* xpre = (float*)((char*)d_ws + 64 * 1024);

    fps_pre_kernel<<<4 + (B_ * N_) / 32, 512, 0, stream>>>(pos, idxs, out_pos,
                                                           x, W_pre, b_pre, xpre);
    conv_kernel<<<B_ * M_, 256, 0, stream>>>(pos, x, xpre, idxs, kp_pos, kp_W,
                                             W_post, b_post, W_sc, b_sc, out_feat);
}

// Round 3
// 1913.103 us; speedup vs baseline: 1.1169x; 1.1169x over previous
//
#include <hip/hip_runtime.h>

#define B_    4
#define N_    8192
#define CIN   128
#define COUT  256
#define M_    2048
#define K_    16
#define DM    64
#define MAXNN 64
#define CAP   128
#define R2    0.01f
#define EXT   0.1f

#define NPRE  1024            // pre-MLP blocks (B_*N_/32)
#define CONV0 (4 + NPRE)      // first conv block id
#define PUB   32              // FPS publish batch (iterations per ready-flag update)

typedef float v2f __attribute__((ext_vector_type(2)));
typedef unsigned long long ull;

// Exact-rounded squared distance matching numpy's op order: (dx*dx + dy*dy) + dz*dz
__device__ __forceinline__ float d2_exact(float ax, float ay, float az,
                                          float bx, float by, float bz) {
    float dx = ax - bx, dy = ay - by, dz = az - bz;
    return __fadd_rn(__fadd_rn(__fmul_rn(dx, dx), __fmul_rn(dy, dy)), __fmul_rn(dz, dz));
}

// DPP u64-key max step (key only: 2 regs through the butterfly)
#define DPP_STEP2(CTRL)                                                                   \
    {                                                                                     \
        unsigned tlo = (unsigned)__builtin_amdgcn_update_dpp(0, (int)klo, CTRL, 0xF, 0xF, true); \
        unsigned thi = (unsigned)__builtin_amdgcn_update_dpp(0, (int)khi, CTRL, 0xF, 0xF, true); \
        unsigned long long tk = ((unsigned long long)thi << 32) | tlo;                    \
        unsigned long long ck = ((unsigned long long)khi << 32) | klo;                    \
        if (tk > ck) { klo = tlo; khi = thi; }                                            \
    }

// Zero the producer-consumer flags each launch (workspace is not assumed clean;
// stream-ordered so it completes before mega_kernel starts).
__global__ void init_kernel(int* __restrict__ flags) {
    if (threadIdx.x < 8) flags[threadIdx.x] = 0;
}

// ---------------- merged kernel ----------------
// blocks 0..3          : FPS, one per cloud (round-1 form: measured-fastest inner loop)
// blocks 4..1027       : pre-MLP (32 rows each); publish flags[4] (done-counter) on exit
// blocks 1028..9219    : conv, id c -> (b = c&3, m = c>>2); sleep-poll until
//                        flags[b] > m (idx ready) AND flags[4] == NPRE (xpre ready)
// FPS publishes flags[b] = m+1 every PUB iterations (threadfence + agent store,
// amortized ~10cy/iter on wave0 only). All blocks carry the 96KB union -> conv
// never co-resides with FPS (no interference with the serial chain).
__global__ __launch_bounds__(512, 2) void mega_kernel(const float* __restrict__ pos,
                                                      int* __restrict__ idx_out,
                                                      float* __restrict__ out_pos,
                                                      const float* __restrict__ x,
                                                      const float* __restrict__ Wp,
                                                      const float* __restrict__ bvec,
                                                      float* __restrict__ xpre,
                                                      const float* __restrict__ kp_pos,
                                                      const float* __restrict__ kp_W,
                                                      const float* __restrict__ W_post,
                                                      const float* __restrict__ b_post,
                                                      const float* __restrict__ W_sc,
                                                      const float* __restrict__ b_sc,
                                                      float* __restrict__ out_feat,
                                                      int* __restrict__ flags) {
    __shared__ union {
        struct { float sx[N_]; float sy[N_]; float sz[N_]; ull slots[2][8]; } f;  // ~96.1 KB
        struct { float Ws[CIN * DM]; float xs[32][CIN]; } p;                      // 48 KB
        struct { int nIdx[CAP]; float nD2[CAP]; int cntS;
                 float infl[MAXNN][K_]; float xj[MAXNN][DM];
                 float sS[K_ * DM]; float featP[4][DM]; float xg[CIN]; } c;       // ~27 KB
    } sh;

    const int t = threadIdx.x;
    const int blk = blockIdx.x;

    if (blk >= CONV0) {
        // ---------------- conv branch (512 threads; compute stages guarded to the
        // original 256-thread shape => bit-path-identical arithmetic) ----------------
        const int cid = blk - CONV0;
        const int cb = cid & 3;
        const int cm = cid >> 2;

        if (t == 0) {
            while (__hip_atomic_load(&flags[cb], __ATOMIC_RELAXED, __HIP_MEMORY_SCOPE_AGENT) <= cm ||
                   __hip_atomic_load(&flags[4], __ATOMIC_RELAXED, __HIP_MEMORY_SCOPE_AGENT) < NPRE) {
                __builtin_amdgcn_s_sleep(64);   // ~4k cycles between polls
            }
            __threadfence();                    // acquire: order/invalidate before data reads
            sh.c.cntS = 0;
        }
        __syncthreads();

        const float* pb = pos + (size_t)cb * N_ * 3;
        const int ctr = idx_out[cb * M_ + cm];
        const float ccx = pb[ctr * 3 + 0], ccy = pb[ctr * 3 + 1], ccz = pb[ctr * 3 + 2];

        // neighbor scan over all N points (stride 512; values identical)
        for (int j = 0; j < N_ / 512; j++) {
            int n = j * 512 + t;
            float x0 = pb[n * 3 + 0], y0 = pb[n * 3 + 1], z0 = pb[n * 3 + 2];
            float d = d2_exact(x0, y0, z0, ccx, ccy, ccz);
            if (d <= R2) {
                int pp = atomicAdd(&sh.c.cntS, 1);
                if (pp < CAP) { sh.c.nIdx[pp] = n; sh.c.nD2[pp] = d; }
            }
        }
        __syncthreads();
        int cnt = sh.c.cntS; if (cnt > CAP) cnt = CAP;
        if (cnt > MAXNN) {
            // rare path: keep the 64 lexicographically-smallest (d2, idx) = stable top_k
            if (t == 0) {
                for (int s = 0; s < MAXNN; s++) {
                    int best = s;
                    for (int q = s + 1; q < cnt; q++) {
                        if (sh.c.nD2[q] < sh.c.nD2[best] ||
                            (sh.c.nD2[q] == sh.c.nD2[best] && sh.c.nIdx[q] < sh.c.nIdx[best])) best = q;
                    }
                    float td = sh.c.nD2[best]; sh.c.nD2[best] = sh.c.nD2[s]; sh.c.nD2[s] = td;
                    int ti = sh.c.nIdx[best]; sh.c.nIdx[best] = sh.c.nIdx[s]; sh.c.nIdx[s] = ti;
                }
            }
            __syncthreads();
            cnt = MAXNN;
        }

        // influence weights (one thread per neighbor)
        if (t < cnt) {
            int n = sh.c.nIdx[t];
            float rx = pb[n * 3 + 0] - ccx, ry = pb[n * 3 + 1] - ccy, rz = pb[n * 3 + 2] - ccz;
#pragma unroll
            for (int k = 0; k < K_; k++) {
                float dx = rx - kp_pos[k * 3 + 0];
                float dy = ry - kp_pos[k * 3 + 1];
                float dz = rz - kp_pos[k * 3 + 2];
                float dist = sqrtf(dx * dx + dy * dy + dz * dz + 1e-12f);
                sh.c.infl[t][k] = fmaxf(1.0f - dist / EXT, 0.0f);
            }
        }
        // stage gathered neighbor features (stride 512)
        for (int i = t; i < cnt * DM; i += 512) {
            int e = i >> 6, d = i & 63;
            sh.c.xj[e][d] = xpre[((size_t)cb * N_ + sh.c.nIdx[e]) * DM + d];
        }
        __syncthreads();

        // s[k][d] = sum_e infl[e][k] * xj[e][d]   (original 256-thread shape)
        if (t < 256) {
#pragma unroll
            for (int p4 = 0; p4 < 4; p4++) {
                int pair = t + p4 * 256;
                int k = pair >> 6, d = pair & 63;
                float acc = 0.f;
                for (int e = 0; e < cnt; e++) acc = fmaf(sh.c.infl[e][k], sh.c.xj[e][d], acc);
                sh.c.sS[pair] = acc;
            }
        }
        __syncthreads();

        // feat[d'] = sum_{k,d} s[k][d] * kp_W[k][d][d']  (4-way k-split)
        if (t < 256) {
            int dprime = t & 63, ks = t >> 6;
            float acc = 0.f;
            for (int k = ks * 4; k < ks * 4 + 4; k++) {
                const float* kw = kp_W + ((size_t)k * DM) * DM + dprime;
#pragma unroll
                for (int d = 0; d < DM; d++) acc = fmaf(sh.c.sS[k * DM + d], kw[d * DM], acc);
            }
            sh.c.featP[ks][dprime] = acc;
        }
        __syncthreads();
        if (t < DM) sh.c.featP[0][t] = sh.c.featP[0][t] + sh.c.featP[1][t] + sh.c.featP[2][t] + sh.c.featP[3][t];
        if (t < CIN) sh.c.xg[t] = x[((size_t)cb * N_ + ctr) * CIN + t];
        __syncthreads();

        if (t < 256) {
            const int o = t;
            float acc = b_post[o] + b_sc[o];
#pragma unroll 8
            for (int d = 0; d < DM; d++) acc = fmaf(sh.c.featP[0][d], W_post[d * COUT + o], acc);
#pragma unroll 8
            for (int cc = 0; cc < CIN; cc++) acc = fmaf(sh.c.xg[cc], W_sc[cc * COUT + o], acc);
            out_feat[((size_t)(cb * M_ + cm)) * COUT + o] = acc;
        }
        return;
    }

    if (blk >= 4) {
        // ---------------- pre-MLP branch: 32 rows per block ----------------
        const size_t rowBase = (size_t)(blk - 4) * 32;
        for (int i = t; i < CIN * DM; i += 512) sh.p.Ws[i] = Wp[i];
        for (int i = t; i < 32 * CIN; i += 512) {
            int r = i >> 7, c = i & 127;
            sh.p.xs[r][c] = x[(rowBase + r) * CIN + c];
        }
        __syncthreads();
        const int col = t & 63, r0 = t >> 6;   // r0 in [0,8)
        float acc[4];
        float bias = bvec[col];
#pragma unroll
        for (int rr = 0; rr < 4; rr++) acc[rr] = bias;
        for (int c = 0; c < CIN; c++) {
            float w = sh.p.Ws[c * DM + col];
#pragma unroll
            for (int rr = 0; rr < 4; rr++) acc[rr] = fmaf(sh.p.xs[r0 + 8 * rr][c], w, acc[rr]);
        }
#pragma unroll
        for (int rr = 0; rr < 4; rr++) xpre[(rowBase + r0 + 8 * rr) * DM + col] = acc[rr];
        // publish: xpre visible (per-thread fence) before the block's done-increment
        __threadfence();
        __syncthreads();
        if (t == 0) atomicAdd(&flags[4], 1);
        return;
    }

    // ---------------- FPS branch (round-1 form: measured-fastest) ----------------
    const int b = blk;
    const float* pb = pos + (size_t)b * N_ * 3;

    v2f px[8], py[8], pz[8], mind[8];
#pragma unroll
    for (int jj = 0; jj < 8; jj++) {
        int n0 = t + (2 * jj) * 512, n1 = n0 + 512;
        float x0 = pb[n0 * 3 + 0], y0 = pb[n0 * 3 + 1], z0 = pb[n0 * 3 + 2];
        float x1 = pb[n1 * 3 + 0], y1 = pb[n1 * 3 + 1], z1 = pb[n1 * 3 + 2];
        px[jj] = (v2f){x0, x1};
        py[jj] = (v2f){y0, y1};
        pz[jj] = (v2f){z0, z1};
        mind[jj] = (v2f){1e30f, 1e30f};
        sh.f.sx[n0] = x0; sh.f.sy[n0] = y0; sh.f.sz[n0] = z0;
        sh.f.sx[n1] = x1; sh.f.sy[n1] = y1; sh.f.sz[n1] = z1;
    }
    float cx = pb[0], cy = pb[1], cz = pb[2];
    if (t == 0) {
        idx_out[b * M_ + 0] = 0;
        float* op = out_pos + ((size_t)(b * M_ + 0)) * 3;
        op[0] = cx; op[1] = cy; op[2] = cz;
    }
    __syncthreads();

    for (int m = 1; m < M_; m++) {
        // fused mind-update + lane-local argmax over 16 pts (8 packed pairs).
        // Ascending slot order => strict > keeps first max => smallest index on ties.
        float bv = -1.0f; int bj = 0;
        {
#pragma clang fp contract(off)
            v2f cx2 = (v2f){cx, cx}, cy2 = (v2f){cy, cy}, cz2 = (v2f){cz, cz};
#pragma unroll
            for (int jj = 0; jj < 8; jj++) {
                v2f dx = px[jj] - cx2, dy = py[jj] - cy2, dz = pz[jj] - cz2;
                v2f d = (dx * dx + dy * dy) + dz * dz;
                v2f mo = mind[jj];
                float n0 = fminf(mo.x, d.x);
                float n1 = fminf(mo.y, d.y);
                mind[jj] = (v2f){n0, n1};
                if (n0 > bv) { bv = n0; bj = 2 * jj; }
                if (n1 > bv) { bv = n1; bj = 2 * jj + 1; }
            }
        }
        const int bn = t + (bj << 9);
        unsigned klo = ~(unsigned)bn;
        unsigned khi = __float_as_uint(bv);

        // wave64 max-reduce via DPP; winner lands in lane 63
        DPP_STEP2(0x111)  // row_shr:1
        DPP_STEP2(0x112)  // row_shr:2
        DPP_STEP2(0x114)  // row_shr:4
        DPP_STEP2(0x118)  // row_shr:8
        DPP_STEP2(0x142)  // row_bcast:15
        DPP_STEP2(0x143)  // row_bcast:31

        // per-wave slot write (double-buffered on m&1)
        ull* sl = sh.f.slots[m & 1];
        if ((t & 63) == 63) sl[t >> 6] = ((ull)khi << 32) | klo;
        __syncthreads();

        // all threads: depth-3 max tree over the 8 wave keys
        ull k0 = sl[0], k1 = sl[1], k2 = sl[2], k3 = sl[3];
        ull k4 = sl[4], k5 = sl[5], k6 = sl[6], k7 = sl[7];
        ull a0 = k0 > k1 ? k0 : k1;
        ull a1 = k2 > k3 ? k2 : k3;
        ull a2 = k4 > k5 ? k4 : k5;
        ull a3 = k6 > k7 ? k6 : k7;
        ull b0 = a0 > a1 ? a0 : a1;
        ull b1 = a2 > a3 ? a2 : a3;
        ull kk = b0 > b1 ? b0 : b1;

        const unsigned widx = ~(unsigned)(kk & 0xFFFFFFFFull);
        // winner coords: same-address LDS broadcast
        cx = sh.f.sx[widx]; cy = sh.f.sy[widx]; cz = sh.f.sz[widx];
        if (t == 0) {
            idx_out[b * M_ + m] = (int)widx;
            float* op = out_pos + ((size_t)(b * M_ + m)) * 3;
            op[0] = cx; op[1] = cy; op[2] = cz;
            // batched publish: make idx_out[.. m] visible, then bump ready-counter.
            // threadfence (vmcnt drain) lands on wave0 once per PUB iters only.
            if ((m & (PUB - 1)) == (PUB - 1)) {
                __threadfence();
                __hip_atomic_store(&flags[b], m + 1, __ATOMIC_RELAXED, __HIP_MEMORY_SCOPE_AGENT);
            }
        }
    }
}

extern "C" void kernel_launch(void* const* d_in, const int* in_sizes, int n_in,
                              void* d_out, int out_size, void* d_ws, size_t ws_size,
                              hipStream_t stream) {
    const float* x      = (const float*)d_in[0];
    const float* pos    = (const float*)d_in[1];
    const float* W_pre  = (const float*)d_in[2];
    const float* b_pre  = (const float*)d_in[3];
    const float* kp_pos = (const float*)d_in[4];
    const float* kp_W   = (const float*)d_in[5];
    const float* W_post = (const float*)d_in[6];
    const float* b_post = (const float*)d_in[7];
    const float* W_sc   = (const float*)d_in[8];
    const float* b_sc   = (const float*)d_in[9];

    float* out_feat = (float*)d_out;
    float* out_pos  = (float*)d_out + (size_t)B_ * M_ * COUT;

    int*   idxs  = (int*)d_ws;                              // 32 KB
    int*   flags = (int*)((char*)d_ws + 48 * 1024);         // 8 ints: ready[0..3], pre_done, pad
    float* xpre  = (float*)((char*)d_ws + 64 * 1024);       // 8 MB

    init_kernel<<<1, 64, 0, stream>>>(flags);
    mega_kernel<<<CONV0 + B_ * M_, 512, 0, stream>>>(pos, idxs, out_pos,
                                                     x, W_pre, b_pre, xpre,
                                                     kp_pos, kp_W, W_post, b_post,
                                                     W_sc, b_sc, out_feat, flags);
}